// Round 8
// baseline (957.404 us; speedup 1.0000x reference)
//
#include <hip/hip_runtime.h>

// Problem constants
#define QD   1280
#define CD   768
#define NH   8
#define NN   2
#define ZZ   2
#define RR   8
#define BFB  16
#define SS   4096
#define DH   160           // QD/NH
#define TT   4             // NN*ZZ
#define OO   32            // NH*TT

typedef __attribute__((ext_vector_type(4))) float f32x4;
typedef __attribute__((ext_vector_type(8))) short short8;   // 8 bf16 = 4 VGPRs (MFMA A/B frag)

// ---------------------------------------------------------------------------
// K1: K/V = lora(ctx3d, W, A, B).  ctx3d[b,t,c] = context[b, t>>1, c] + pe[t&1, c]
// grid (5 jtiles, 4 t, 16 b), 256 thr. Outputs Kf/Vf [16][4][1280] f32.
// ---------------------------------------------------------------------------
__global__ __launch_bounds__(256) void kv_kernel(
    const float* __restrict__ ctx, const float* __restrict__ pe,
    const float* __restrict__ Wk, const float* __restrict__ Ak, const float* __restrict__ Bk,
    const float* __restrict__ Wv, const float* __restrict__ Av, const float* __restrict__ Bv,
    float* __restrict__ Kf, float* __restrict__ Vf)
{
    const int jt = blockIdx.x, t = blockIdx.y, b = blockIdx.z;
    const int n = t >> 1, z = t & 1;
    const int tid = threadIdx.x;
    __shared__ float sctx[CD];
    __shared__ float sa[16];     // a_k[0..7], a_v[8..15]

    for (int c = tid; c < CD; c += 256)
        sctx[c] = ctx[(b * NN + n) * CD + c] + pe[z * CD + c];
    __syncthreads();

    const int wave = tid >> 6, lane = tid & 63;
    for (int q = 0; q < 4; q++) {
        const int idx = wave * 4 + q;                 // 0..15
        const float* Arow = (idx < 8 ? Ak : Av) + (idx & 7) * CD;
        float p = 0.f;
        for (int c = lane; c < CD; c += 64) p += sctx[c] * Arow[c];
        for (int off = 32; off; off >>= 1) p += __shfl_down(p, off);
        if (lane == 0) sa[idx] = p;
    }
    __syncthreads();

    const int j = jt * 256 + tid;
    float accK = 0.f, accV = 0.f;
    {
        f32x4 bk0 = *(const f32x4*)(Bk + j * RR);
        f32x4 bk1 = *(const f32x4*)(Bk + j * RR + 4);
        f32x4 bv0 = *(const f32x4*)(Bv + j * RR);
        f32x4 bv1 = *(const f32x4*)(Bv + j * RR + 4);
#pragma unroll
        for (int r = 0; r < 4; r++) {
            accK += sa[r] * bk0[r] + sa[r + 4] * bk1[r];
            accV += sa[8 + r] * bv0[r] + sa[12 + r] * bv1[r];
        }
    }
    const f32x4* wkrow = (const f32x4*)(Wk + j * CD);
    const f32x4* wvrow = (const f32x4*)(Wv + j * CD);
    for (int c4 = 0; c4 < CD / 4; c4++) {
        f32x4 wk = wkrow[c4], wv = wvrow[c4];
#pragma unroll
        for (int u = 0; u < 4; u++) {
            float xc = sctx[c4 * 4 + u];
            accK += xc * wk[u];
            accV += xc * wv[u];
        }
    }
    Kf[(b * TT + t) * QD + j] = accK;
    Vf[(b * TT + t) * QD + j] = accV;
}

// ---------------------------------------------------------------------------
// K2: P[b][k][h*4+t] and VW[b][ht][j], t-batched.
// Each block computes ALL 4 t for its (which, h, b) -> Wq/Wout slices read
// once per (h,b); P-store is one contiguous f32x4 per j.
// grid (2 which, 8 h, 16 b), 256 thr.
// ---------------------------------------------------------------------------
__global__ __launch_bounds__(256) void pvw_kernel(
    const float* __restrict__ Wq, const float* __restrict__ Wout,
    const float* __restrict__ Kf, const float* __restrict__ Vf,
    float* __restrict__ P, float* __restrict__ VW)
{
    const int which = blockIdx.x, h = blockIdx.y, b = blockIdx.z;
    const int tid = threadIdx.x;
    __shared__ float sv[TT][DH];

    const float* src = (which == 0 ? Kf : Vf);
    for (int e = tid; e < TT * DH; e += 256) {
        int t = e / DH, d = e % DH;
        sv[t][d] = src[(b * TT + t) * QD + h * DH + d];
    }
    __syncthreads();

    if (which == 0) {
        float acc[5][4];
#pragma unroll
        for (int i = 0; i < 5; i++)
#pragma unroll
            for (int t = 0; t < 4; t++) acc[i][t] = 0.f;

#pragma unroll 2
        for (int d = 0; d < DH; d++) {
            const float* wqrow = Wq + (h * DH + d) * QD;
            float wq[5];
#pragma unroll
            for (int i = 0; i < 5; i++) wq[i] = wqrow[tid + 256 * i];
#pragma unroll
            for (int i = 0; i < 5; i++)
#pragma unroll
                for (int t = 0; t < 4; t++)
                    acc[i][t] = fmaf(sv[t][d], wq[i], acc[i][t]);
        }
#pragma unroll
        for (int i = 0; i < 5; i++) {
            int j = tid + 256 * i;
            f32x4 v = {acc[i][0], acc[i][1], acc[i][2], acc[i][3]};
            *(f32x4*)(P + ((size_t)(b * QD + j)) * OO + h * 4) = v;
        }
    } else {
        float acc[5][4];
#pragma unroll
        for (int i = 0; i < 5; i++)
#pragma unroll
            for (int t = 0; t < 4; t++) acc[i][t] = 0.f;

        for (int d4 = 0; d4 < DH / 4; d4++) {
#pragma unroll
            for (int i = 0; i < 5; i++) {
                int j = tid + 256 * i;
                f32x4 w = *(const f32x4*)(Wout + (size_t)j * QD + h * DH + d4 * 4);
#pragma unroll
                for (int u = 0; u < 4; u++)
#pragma unroll
                    for (int t = 0; t < 4; t++)
                        acc[i][t] = fmaf(sv[t][d4 * 4 + u], w[u], acc[i][t]);
            }
        }
#pragma unroll
        for (int i = 0; i < 5; i++) {
            int j = tid + 256 * i;
#pragma unroll
            for (int t = 0; t < 4; t++)
                VW[((size_t)b * OO + h * 4 + t) * QD + j] = acc[i][t];
        }
    }
}

// ---------------------------------------------------------------------------
// K2b: pre-pack P (f32 [b][k][o]) into bf16 MFMA B-fragments.
// Pfrag[b][ks][nt][lane][j] where k = ks*32 + (lane>>4)*8 + j, o = nt*16+(lane&15).
// Pairs (j even, j+1) packed with v_cvt_pk_bf16_f32 — SAME pairing as the
// A-side in scores_kernel, so the dot pairing is lo/hi-convention-invariant.
// grid (80 = ks*2+nt, 16 b), 64 thr.
// ---------------------------------------------------------------------------
__global__ __launch_bounds__(64) void pfrag_kernel(
    const float* __restrict__ P, unsigned* __restrict__ Pfrag)
{
    const int ksnt = blockIdx.x;          // 0..79
    const int b = blockIdx.y;
    const int ks = ksnt >> 1, nt = ksnt & 1;
    const int l = threadIdx.x;
    const int k0 = ks * 32 + (l >> 4) * 8;
    const int o  = nt * 16 + (l & 15);

    const float* Pb = P + ((size_t)b * QD + k0) * OO + o;
    float v[8];
#pragma unroll
    for (int j = 0; j < 8; j++) v[j] = Pb[j * OO];

    unsigned d[4];
#pragma unroll
    for (int i = 0; i < 4; i++)
        asm("v_cvt_pk_bf16_f32 %0, %1, %2" : "=v"(d[i]) : "v"(v[2 * i]), "v"(v[2 * i + 1]));

    unsigned* dst = Pfrag + ((size_t)(b * 80 + ksnt) * 64 + l) * 4;
    dst[0] = d[0]; dst[1] = d[1]; dst[2] = d[2]; dst[3] = d[3];
}

// ---------------------------------------------------------------------------
// K3: scores via bf16 MFMA, k-split x2.
//
// Round-8 change: __launch_bounds__(512, 6) instead of (512, 8). The hard
// 64-VGPR cap of ",8" was a spill risk (hand count ~55-60 live VGPRs BEFORE
// the compiler's software-pipelining doubles the load buffers). ",6" caps at
// 85 VGPR — spill-proof margin — while keeping >=6 waves/SIMD of TLP.
//
// A-frag: lane l -> row (l&15), k = kb + (l>>4)*8 + j  (cvt_pk from f32 x).
// B-frag: pre-packed by pfrag_kernel (same j pairing).
// C: col = lane&15 (=o), row = (lane>>4)*4 + reg   [m89 layout].
//
// grid (64 s-tiles of 64 rows, 16 b), 512 thr (waves 0-3: k<640, 4-7: rest).
// ---------------------------------------------------------------------------
__global__ __launch_bounds__(512, 6) void scores_kernel(
    const float* __restrict__ x, const unsigned* __restrict__ Pfrag,
    float* __restrict__ Wgt)
{
    const int b = blockIdx.y;
    const int tid = threadIdx.x;
    const int w = tid >> 6, l = tid & 63;
    const int g = w & 3;              // row group 0..3
    const int khalf = w >> 2;         // k-half 0/1
    const int lg = l >> 4, lo16 = l & 15;
    const int rowbase = blockIdx.x * 64 + g * 16;       // per-batch s of this wave
    const float scale = 0.07905694150420949f;           // 1/sqrt(160)

    __shared__ float red[4][64][9];   // 9-pad -> conflict-free

    f32x4 acc0 = (f32x4){0.f, 0.f, 0.f, 0.f};
    f32x4 acc1 = (f32x4){0.f, 0.f, 0.f, 0.f};

    const float* xr0 = x + ((size_t)b * SS + rowbase + lo16) * QD + khalf * 640;
    const unsigned* Pfb = Pfrag + (size_t)b * 80 * 256 + (size_t)l * 4
                        + (size_t)khalf * 40 * 256;

    union U { unsigned u[4]; short8 s; };

    for (int ks = 0; ks < 20; ++ks) {
        const int kb = ks * 32 + lg * 8;
        f32x4 x00 = *(const f32x4*)(xr0 + kb);
        f32x4 x01 = *(const f32x4*)(xr0 + kb + 4);
        short8 bf0 = *(const short8*)(Pfb + (size_t)(ks * 2 + 0) * 256);
        short8 bf1 = *(const short8*)(Pfb + (size_t)(ks * 2 + 1) * 256);

        U a0;
        asm("v_cvt_pk_bf16_f32 %0, %1, %2" : "=v"(a0.u[0]) : "v"(x00[0]), "v"(x00[1]));
        asm("v_cvt_pk_bf16_f32 %0, %1, %2" : "=v"(a0.u[1]) : "v"(x00[2]), "v"(x00[3]));
        asm("v_cvt_pk_bf16_f32 %0, %1, %2" : "=v"(a0.u[2]) : "v"(x01[0]), "v"(x01[1]));
        asm("v_cvt_pk_bf16_f32 %0, %1, %2" : "=v"(a0.u[3]) : "v"(x01[2]), "v"(x01[3]));

        acc0 = __builtin_amdgcn_mfma_f32_16x16x32_bf16(a0.s, bf0, acc0, 0, 0, 0);
        acc1 = __builtin_amdgcn_mfma_f32_16x16x32_bf16(a0.s, bf1, acc1, 0, 0, 0);
    }

    // cross-khalf reduce: high waves deposit partials, low waves add.
    if (khalf == 1) {
#pragma unroll
        for (int r = 0; r < 4; ++r) {
            red[g][l][r]     = acc0[r];
            red[g][l][4 + r] = acc1[r];
        }
    }
    __syncthreads();
    if (khalf == 1) return;

#pragma unroll
    for (int r = 0; r < 4; ++r) {
        acc0[r] += red[g][l][r];
        acc1[r] += red[g][l][4 + r];
    }

    // epilogue: lane holds rows (rowbase + lg*4 + r) at o = lo16 and lo16+16.
    // z = o&1 = l&1 (same parity for both N-tiles). op0 = (1/8) * sum of the
    // 16 even-o sigmas; reduce across the 16-lane group via shfl_xor (masks
    // 1,2,4,8 stay within the lg group, which owns these 4 rows).
#pragma unroll
    for (int r = 0; r < 4; ++r) {
        float s0v = 1.f / (1.f + __expf(-acc0[r] * scale));
        float s1v = 1.f / (1.f + __expf(-acc1[r] * scale));
        float contrib = ((l & 1) == 0) ? (s0v + s1v) : 0.f;
        contrib += __shfl_xor(contrib, 1);
        contrib += __shfl_xor(contrib, 2);
        contrib += __shfl_xor(contrib, 4);
        contrib += __shfl_xor(contrib, 8);
        float op0 = fminf(contrib * 0.125f, 1.f);
        float t1 = (l & 1) ? (1.f - op0) : 1.f;
        const int R = rowbase + lg * 4 + r;
        float* Wr = Wgt + ((size_t)b * SS + R) * OO;
        Wr[lo16]      = s0v * t1;
        Wr[lo16 + 16] = s1v * t1;
    }
}

// ---------------------------------------------------------------------------
// K4: out[b,s,j] = x[b,s,j] + bout[j] + sum_ht w[b,s,ht] * VW[b,ht,j]
//
// Round-8 change: weights staged to LDS once per block (8 KB, one barrier;
// per-row reads are uniform-address broadcasts = conflict-free, and lgkm is
// DS-only — no SMEM mixing, no SGPR pressure from 32 s_loads/row). Rows
// unrolled x4 so 4 x-loads are in flight per lane: ~40 KB/CU outstanding,
// well above the ~10 KB needed to saturate this CU's HBM share.
//
// grid (64 s-tiles of 64, 16 b), 320 thr (QD/4 float4 chunks, 16B/lane).
// Thread keeps VW[b][*][4*tid..4*tid+3] in 128 VGPRs.
// ---------------------------------------------------------------------------
__global__ __launch_bounds__(320) void out_kernel(
    const float* __restrict__ x, const float* __restrict__ bout,
    const float* __restrict__ VW, const float* __restrict__ Wgt,
    float* __restrict__ out)
{
    const int b = blockIdx.y;
    const int s0 = blockIdx.x * 64;
    const int tid = threadIdx.x;

    __shared__ float wsm[64][OO];   // 8 KB

    f32x4 vw[32];
    {
        const float* VWb = VW + (size_t)b * OO * QD + 4 * tid;
#pragma unroll
        for (int ht = 0; ht < 32; ht++) vw[ht] = *(const f32x4*)(VWb + ht * QD);
    }
    f32x4 bo = *(const f32x4*)(bout + 4 * tid);

    // stage the 64x32 weight tile (coalesced)
    for (int e = tid; e < 64 * OO; e += 320)
        wsm[e >> 5][e & 31] = Wgt[((size_t)b * SS + s0 + (e >> 5)) * OO + (e & 31)];
    __syncthreads();

    const size_t base = ((size_t)b * SS + s0) * QD + 4 * tid;

#pragma unroll 4
    for (int row = 0; row < 64; ++row) {
        f32x4 acc = bo + *(const f32x4*)(x + base + (size_t)row * QD);
#pragma unroll
        for (int ht = 0; ht < 32; ht++) {
            float wv_ = wsm[row][ht];     // uniform addr -> broadcast, no conflict
            acc += wv_ * vw[ht];
        }
        *(f32x4*)(out + base + (size_t)row * QD) = acc;
    }
}

// ---------------------------------------------------------------------------
extern "C" void kernel_launch(void* const* d_in, const int* in_sizes, int n_in,
                              void* d_out, int out_size, void* d_ws, size_t ws_size,
                              hipStream_t stream) {
    const float* x    = (const float*)d_in[0];
    const float* ctx  = (const float*)d_in[1];
    const float* Wq   = (const float*)d_in[2];
    const float* Wk   = (const float*)d_in[3];
    const float* Ak   = (const float*)d_in[4];
    const float* Bk   = (const float*)d_in[5];
    const float* Wv   = (const float*)d_in[6];
    const float* Av   = (const float*)d_in[7];
    const float* Bv   = (const float*)d_in[8];
    const float* pe   = (const float*)d_in[9];
    const float* Wout = (const float*)d_in[10];
    const float* bout = (const float*)d_in[11];
    float* out = (float*)d_out;

    // Workspace layout (floats):
    // Kf 81920 | Vf 81920 | P 655360 | VW 655360 | Wgt 2097152 | Pfrag 327680
    float* ws = (float*)d_ws;
    float* Kf = ws;
    float* Vf = ws + 81920;
    float* P  = ws + 163840;
    float* VW = ws + 819200;
    float* Wg = ws + 1474560;
    unsigned* Pfrag = (unsigned*)(ws + 3571712);   // total 3,899,392 floats = 15.6 MB

    kv_kernel<<<dim3(5, 4, 16), 256, 0, stream>>>(ctx, pe, Wk, Ak, Bk, Wv, Av, Bv, Kf, Vf);
    pvw_kernel<<<dim3(2, 8, 16), 256, 0, stream>>>(Wq, Wout, Kf, Vf, P, VW);
    pfrag_kernel<<<dim3(80, 16), 64, 0, stream>>>(P, Pfrag);
    scores_kernel<<<dim3(64, 16), 512, 0, stream>>>(x, Pfrag, Wg);
    out_kernel<<<dim3(64, 16), 320, 0, stream>>>(x, bout, VW, Wg, out);
}

// Round 9
// 955.502 us; speedup vs baseline: 1.0020x; 1.0020x over previous
//
#include <hip/hip_runtime.h>

// Problem constants
#define QD   1280
#define CD   768
#define NH   8
#define NN   2
#define ZZ   2
#define RR   8
#define BFB  16
#define SS   4096
#define DH   160           // QD/NH
#define TT   4             // NN*ZZ
#define OO   32            // NH*TT

typedef __attribute__((ext_vector_type(4))) float f32x4;
typedef __attribute__((ext_vector_type(8))) short short8;   // 8 bf16 = 4 VGPRs (MFMA A/B frag)

// ---------------------------------------------------------------------------
// K1: K/V = lora(ctx3d, W, A, B).  ctx3d[b,t,c] = context[b, t>>1, c] + pe[t&1, c]
// grid (5 jtiles, 4 t, 16 b), 256 thr. Outputs Kf/Vf [16][4][1280] f32.
// ---------------------------------------------------------------------------
__global__ __launch_bounds__(256) void kv_kernel(
    const float* __restrict__ ctx, const float* __restrict__ pe,
    const float* __restrict__ Wk, const float* __restrict__ Ak, const float* __restrict__ Bk,
    const float* __restrict__ Wv, const float* __restrict__ Av, const float* __restrict__ Bv,
    float* __restrict__ Kf, float* __restrict__ Vf)
{
    const int jt = blockIdx.x, t = blockIdx.y, b = blockIdx.z;
    const int n = t >> 1, z = t & 1;
    const int tid = threadIdx.x;
    __shared__ float sctx[CD];
    __shared__ float sa[16];     // a_k[0..7], a_v[8..15]

    for (int c = tid; c < CD; c += 256)
        sctx[c] = ctx[(b * NN + n) * CD + c] + pe[z * CD + c];
    __syncthreads();

    const int wave = tid >> 6, lane = tid & 63;
    for (int q = 0; q < 4; q++) {
        const int idx = wave * 4 + q;                 // 0..15
        const float* Arow = (idx < 8 ? Ak : Av) + (idx & 7) * CD;
        float p = 0.f;
        for (int c = lane; c < CD; c += 64) p += sctx[c] * Arow[c];
        for (int off = 32; off; off >>= 1) p += __shfl_down(p, off);
        if (lane == 0) sa[idx] = p;
    }
    __syncthreads();

    const int j = jt * 256 + tid;
    float accK = 0.f, accV = 0.f;
    {
        f32x4 bk0 = *(const f32x4*)(Bk + j * RR);
        f32x4 bk1 = *(const f32x4*)(Bk + j * RR + 4);
        f32x4 bv0 = *(const f32x4*)(Bv + j * RR);
        f32x4 bv1 = *(const f32x4*)(Bv + j * RR + 4);
#pragma unroll
        for (int r = 0; r < 4; r++) {
            accK += sa[r] * bk0[r] + sa[r + 4] * bk1[r];
            accV += sa[8 + r] * bv0[r] + sa[12 + r] * bv1[r];
        }
    }
    const f32x4* wkrow = (const f32x4*)(Wk + j * CD);
    const f32x4* wvrow = (const f32x4*)(Wv + j * CD);
    for (int c4 = 0; c4 < CD / 4; c4++) {
        f32x4 wk = wkrow[c4], wv = wvrow[c4];
#pragma unroll
        for (int u = 0; u < 4; u++) {
            float xc = sctx[c4 * 4 + u];
            accK += xc * wk[u];
            accV += xc * wv[u];
        }
    }
    Kf[(b * TT + t) * QD + j] = accK;
    Vf[(b * TT + t) * QD + j] = accV;
}

// ---------------------------------------------------------------------------
// K2: P[b][k][h*4+t] and VW[b][ht][j], t-batched.
// Each block computes ALL 4 t for its (which, h, b) -> Wq/Wout slices read
// once per (h,b); P-store is one contiguous f32x4 per j.
// grid (2 which, 8 h, 16 b), 256 thr.
// ---------------------------------------------------------------------------
__global__ __launch_bounds__(256) void pvw_kernel(
    const float* __restrict__ Wq, const float* __restrict__ Wout,
    const float* __restrict__ Kf, const float* __restrict__ Vf,
    float* __restrict__ P, float* __restrict__ VW)
{
    const int which = blockIdx.x, h = blockIdx.y, b = blockIdx.z;
    const int tid = threadIdx.x;
    __shared__ float sv[TT][DH];

    const float* src = (which == 0 ? Kf : Vf);
    for (int e = tid; e < TT * DH; e += 256) {
        int t = e / DH, d = e % DH;
        sv[t][d] = src[(b * TT + t) * QD + h * DH + d];
    }
    __syncthreads();

    if (which == 0) {
        float acc[5][4];
#pragma unroll
        for (int i = 0; i < 5; i++)
#pragma unroll
            for (int t = 0; t < 4; t++) acc[i][t] = 0.f;

#pragma unroll 2
        for (int d = 0; d < DH; d++) {
            const float* wqrow = Wq + (h * DH + d) * QD;
            float wq[5];
#pragma unroll
            for (int i = 0; i < 5; i++) wq[i] = wqrow[tid + 256 * i];
#pragma unroll
            for (int i = 0; i < 5; i++)
#pragma unroll
                for (int t = 0; t < 4; t++)
                    acc[i][t] = fmaf(sv[t][d], wq[i], acc[i][t]);
        }
#pragma unroll
        for (int i = 0; i < 5; i++) {
            int j = tid + 256 * i;
            f32x4 v = {acc[i][0], acc[i][1], acc[i][2], acc[i][3]};
            *(f32x4*)(P + ((size_t)(b * QD + j)) * OO + h * 4) = v;
        }
    } else {
        float acc[5][4];
#pragma unroll
        for (int i = 0; i < 5; i++)
#pragma unroll
            for (int t = 0; t < 4; t++) acc[i][t] = 0.f;

        for (int d4 = 0; d4 < DH / 4; d4++) {
#pragma unroll
            for (int i = 0; i < 5; i++) {
                int j = tid + 256 * i;
                f32x4 w = *(const f32x4*)(Wout + (size_t)j * QD + h * DH + d4 * 4);
#pragma unroll
                for (int u = 0; u < 4; u++)
#pragma unroll
                    for (int t = 0; t < 4; t++)
                        acc[i][t] = fmaf(sv[t][d4 * 4 + u], w[u], acc[i][t]);
            }
        }
#pragma unroll
        for (int i = 0; i < 5; i++) {
            int j = tid + 256 * i;
#pragma unroll
            for (int t = 0; t < 4; t++)
                VW[((size_t)b * OO + h * 4 + t) * QD + j] = acc[i][t];
        }
    }
}

// ---------------------------------------------------------------------------
// K2b: pre-pack P (f32 [b][k][o]) into bf16 MFMA B-fragments.
// Pfrag[b][ks][nt][lane][j] where k = ks*32 + (lane>>4)*8 + j, o = nt*16+(lane&15).
// Pairs (j even, j+1) packed with v_cvt_pk_bf16_f32 — SAME pairing as the
// A-side in scores_kernel, so the dot pairing is lo/hi-convention-invariant.
// grid (80 = ks*2+nt, 16 b), 64 thr.
// ---------------------------------------------------------------------------
__global__ __launch_bounds__(64) void pfrag_kernel(
    const float* __restrict__ P, unsigned* __restrict__ Pfrag)
{
    const int ksnt = blockIdx.x;          // 0..79
    const int b = blockIdx.y;
    const int ks = ksnt >> 1, nt = ksnt & 1;
    const int l = threadIdx.x;
    const int k0 = ks * 32 + (l >> 4) * 8;
    const int o  = nt * 16 + (l & 15);

    const float* Pb = P + ((size_t)b * QD + k0) * OO + o;
    float v[8];
#pragma unroll
    for (int j = 0; j < 8; j++) v[j] = Pb[j * OO];

    unsigned d[4];
#pragma unroll
    for (int i = 0; i < 4; i++)
        asm("v_cvt_pk_bf16_f32 %0, %1, %2" : "=v"(d[i]) : "v"(v[2 * i]), "v"(v[2 * i + 1]));

    unsigned* dst = Pfrag + ((size_t)(b * 80 + ksnt) * 64 + l) * 4;
    dst[0] = d[0]; dst[1] = d[1]; dst[2] = d[2]; dst[3] = d[3];
}

// ---------------------------------------------------------------------------
// K3: scores via bf16 MFMA, k-split x2.  (reverted to the round-7 config —
// __launch_bounds__(512, 8) — so the only change vs the 847us baseline is
// the out_kernel spill fix.)
//
// A-frag: lane l -> row (l&15), k = kb + (l>>4)*8 + j  (cvt_pk from f32 x).
// B-frag: pre-packed by pfrag_kernel (same j pairing).
// C: col = lane&15 (=o), row = (lane>>4)*4 + reg   [m89 layout].
//
// grid (64 s-tiles of 64 rows, 16 b), 512 thr (waves 0-3: k<640, 4-7: rest).
// ---------------------------------------------------------------------------
__global__ __launch_bounds__(512, 8) void scores_kernel(
    const float* __restrict__ x, const unsigned* __restrict__ Pfrag,
    float* __restrict__ Wgt)
{
    const int b = blockIdx.y;
    const int tid = threadIdx.x;
    const int w = tid >> 6, l = tid & 63;
    const int g = w & 3;              // row group 0..3
    const int khalf = w >> 2;         // k-half 0/1
    const int lg = l >> 4, lo16 = l & 15;
    const int rowbase = blockIdx.x * 64 + g * 16;       // per-batch s of this wave
    const float scale = 0.07905694150420949f;           // 1/sqrt(160)

    __shared__ float red[4][64][9];   // 9-pad -> conflict-free

    f32x4 acc0 = (f32x4){0.f, 0.f, 0.f, 0.f};
    f32x4 acc1 = (f32x4){0.f, 0.f, 0.f, 0.f};

    const float* xr0 = x + ((size_t)b * SS + rowbase + lo16) * QD + khalf * 640;
    const unsigned* Pfb = Pfrag + (size_t)b * 80 * 256 + (size_t)l * 4
                        + (size_t)khalf * 40 * 256;

    union U { unsigned u[4]; short8 s; };

    for (int ks = 0; ks < 20; ++ks) {
        const int kb = ks * 32 + lg * 8;
        f32x4 x00 = *(const f32x4*)(xr0 + kb);
        f32x4 x01 = *(const f32x4*)(xr0 + kb + 4);
        short8 bf0 = *(const short8*)(Pfb + (size_t)(ks * 2 + 0) * 256);
        short8 bf1 = *(const short8*)(Pfb + (size_t)(ks * 2 + 1) * 256);

        U a0;
        asm("v_cvt_pk_bf16_f32 %0, %1, %2" : "=v"(a0.u[0]) : "v"(x00[0]), "v"(x00[1]));
        asm("v_cvt_pk_bf16_f32 %0, %1, %2" : "=v"(a0.u[1]) : "v"(x00[2]), "v"(x00[3]));
        asm("v_cvt_pk_bf16_f32 %0, %1, %2" : "=v"(a0.u[2]) : "v"(x01[0]), "v"(x01[1]));
        asm("v_cvt_pk_bf16_f32 %0, %1, %2" : "=v"(a0.u[3]) : "v"(x01[2]), "v"(x01[3]));

        acc0 = __builtin_amdgcn_mfma_f32_16x16x32_bf16(a0.s, bf0, acc0, 0, 0, 0);
        acc1 = __builtin_amdgcn_mfma_f32_16x16x32_bf16(a0.s, bf1, acc1, 0, 0, 0);
    }

    // cross-khalf reduce: high waves deposit partials, low waves add.
    if (khalf == 1) {
#pragma unroll
        for (int r = 0; r < 4; ++r) {
            red[g][l][r]     = acc0[r];
            red[g][l][4 + r] = acc1[r];
        }
    }
    __syncthreads();
    if (khalf == 1) return;

#pragma unroll
    for (int r = 0; r < 4; ++r) {
        acc0[r] += red[g][l][r];
        acc1[r] += red[g][l][4 + r];
    }

    // epilogue: lane holds rows (rowbase + lg*4 + r) at o = lo16 and lo16+16.
    // z = o&1 = l&1 (same parity for both N-tiles). op0 = (1/8) * sum of the
    // 16 even-o sigmas; reduce across the 16-lane group via shfl_xor (masks
    // 1,2,4,8 stay within the lg group, which owns these 4 rows).
#pragma unroll
    for (int r = 0; r < 4; ++r) {
        float s0v = 1.f / (1.f + __expf(-acc0[r] * scale));
        float s1v = 1.f / (1.f + __expf(-acc1[r] * scale));
        float contrib = ((l & 1) == 0) ? (s0v + s1v) : 0.f;
        contrib += __shfl_xor(contrib, 1);
        contrib += __shfl_xor(contrib, 2);
        contrib += __shfl_xor(contrib, 4);
        contrib += __shfl_xor(contrib, 8);
        float op0 = fminf(contrib * 0.125f, 1.f);
        float t1 = (l & 1) ? (1.f - op0) : 1.f;
        const int R = rowbase + lg * 4 + r;
        float* Wr = Wgt + ((size_t)b * SS + R) * OO;
        Wr[lo16]      = s0v * t1;
        Wr[lo16 + 16] = s1v * t1;
    }
}

// ---------------------------------------------------------------------------
// K4: out[b,s,j] = x[b,s,j] + bout[j] + sum_ht w[b,s,ht] * VW[b,ht,j]
//
// Round-9 fix: round-8's VGPR_Count=84 proved vw[32] (128 VGPRs) SPILLED —
// the LDS/barrier structure flipped the allocator to a 6-waves/SIMD target
// (512/6=85). __launch_bounds__(320, 2) caps at 2 waves/SIMD -> 256 VGPRs,
// guaranteeing vw stays resident (~200 needed). Occupancy is low by design;
// rows unrolled x8 gives 8 independent 16B x-loads in flight per lane
// (~40 KB/CU outstanding > ~22 KB BW-latency product) to saturate HBM on
// ILP alone. LDS weight staging kept (broadcast ds_reads ~1 LDS-clock).
//
// grid (64 s-tiles of 64, 16 b), 320 thr (QD/4 float4 chunks, 16B/lane).
// ---------------------------------------------------------------------------
__global__ __launch_bounds__(320, 2) void out_kernel(
    const float* __restrict__ x, const float* __restrict__ bout,
    const float* __restrict__ VW, const float* __restrict__ Wgt,
    float* __restrict__ out)
{
    const int b = blockIdx.y;
    const int s0 = blockIdx.x * 64;
    const int tid = threadIdx.x;

    __shared__ float wsm[64][OO];   // 8 KB

    f32x4 vw[32];
    {
        const float* VWb = VW + (size_t)b * OO * QD + 4 * tid;
#pragma unroll
        for (int ht = 0; ht < 32; ht++) vw[ht] = *(const f32x4*)(VWb + ht * QD);
    }
    f32x4 bo = *(const f32x4*)(bout + 4 * tid);

    // stage the 64x32 weight tile (coalesced)
    for (int e = tid; e < 64 * OO; e += 320)
        wsm[e >> 5][e & 31] = Wgt[((size_t)b * SS + s0 + (e >> 5)) * OO + (e & 31)];
    __syncthreads();

    const size_t base = ((size_t)b * SS + s0) * QD + 4 * tid;

#pragma unroll 8
    for (int row = 0; row < 64; ++row) {
        f32x4 acc = bo + *(const f32x4*)(x + base + (size_t)row * QD);
#pragma unroll
        for (int ht = 0; ht < 32; ht++) {
            float wv_ = wsm[row][ht];     // uniform addr -> broadcast, no conflict
            acc += wv_ * vw[ht];
        }
        *(f32x4*)(out + base + (size_t)row * QD) = acc;
    }
}

// ---------------------------------------------------------------------------
extern "C" void kernel_launch(void* const* d_in, const int* in_sizes, int n_in,
                              void* d_out, int out_size, void* d_ws, size_t ws_size,
                              hipStream_t stream) {
    const float* x    = (const float*)d_in[0];
    const float* ctx  = (const float*)d_in[1];
    const float* Wq   = (const float*)d_in[2];
    const float* Wk   = (const float*)d_in[3];
    const float* Ak   = (const float*)d_in[4];
    const float* Bk   = (const float*)d_in[5];
    const float* Wv   = (const float*)d_in[6];
    const float* Av   = (const float*)d_in[7];
    const float* Bv   = (const float*)d_in[8];
    const float* pe   = (const float*)d_in[9];
    const float* Wout = (const float*)d_in[10];
    const float* bout = (const float*)d_in[11];
    float* out = (float*)d_out;

    // Workspace layout (floats):
    // Kf 81920 | Vf 81920 | P 655360 | VW 655360 | Wgt 2097152 | Pfrag 327680
    float* ws = (float*)d_ws;
    float* Kf = ws;
    float* Vf = ws + 81920;
    float* P  = ws + 163840;
    float* VW = ws + 819200;
    float* Wg = ws + 1474560;
    unsigned* Pfrag = (unsigned*)(ws + 3571712);   // total 3,899,392 floats = 15.6 MB

    kv_kernel<<<dim3(5, 4, 16), 256, 0, stream>>>(ctx, pe, Wk, Ak, Bk, Wv, Av, Bv, Kf, Vf);
    pvw_kernel<<<dim3(2, 8, 16), 256, 0, stream>>>(Wq, Wout, Kf, Vf, P, VW);
    pfrag_kernel<<<dim3(80, 16), 64, 0, stream>>>(P, Pfrag);
    scores_kernel<<<dim3(64, 16), 512, 0, stream>>>(x, Pfrag, Wg);
    out_kernel<<<dim3(64, 16), 320, 0, stream>>>(x, bout, VW, Wg, out);
}